// Round 12
// baseline (742.629 us; speedup 1.0000x reference)
//
#include <hip/hip_runtime.h>
#include <hip/hip_bf16.h>

typedef __hip_bfloat16 bf16;
typedef __bf16 nbf;
typedef nbf bf16x8 __attribute__((ext_vector_type(8)));
typedef float f32x4 __attribute__((ext_vector_type(4)));

#define NNODE 10000
#define DDEG  15
#define EE    320
#define NH    5
#define OUTD  30
#define PCOLS 1920   // 6*E : [Qin|Kin|Vin|Qout|Kout|Vout]
#define KF    642    // 2*E + 2 (alpha columns)
#define TSTB  648    // padded bf16 T row stride (16B-aligned rows)

// ---------------------------------------------------------------------------
// prep: ONE launch = inline dtype detect (per-block, deterministic) +
// X convert + 3 transposes + 18 segment converts. Block ranges by blockIdx.
// ---------------------------------------------------------------------------
#define NSEG 18
struct PrepTab {
    const void* seg_src[NSEG];
    void*       seg_dst[NSEG];
    int         seg_n[NSEG];
    int         seg_tobf[NSEG];
    int         seg_blocks[NSEG];
    const void* xsrc; nbf* xdst; int xblocks;
    const void* tsrc0; const void* tsrc1; const void* tsrc2; nbf* tdst;
    int* flag;
};

__global__ __launch_bounds__(256) void prep_kernel(PrepTab t)
{
    __shared__ int cnt_s;
    __shared__ __align__(16) nbf tile[32][33];
    if (threadIdx.x == 0) cnt_s = 0;
    __syncthreads();
    {
        const unsigned int* Xw = (const unsigned int*)t.xsrc;
        int local = 0;
        for (int i = threadIdx.x; i < 1024; i += 256) {
            unsigned int lo = Xw[i] & 0xFFFFu;
            int e = (int)((lo >> 7) & 0xFFu);
            if (e >= 100 && e <= 140) local++;
        }
        atomicAdd(&cnt_s, local);
    }
    __syncthreads();
    const int f = cnt_s > 512;
    int b = blockIdx.x;
    if (b == 0 && threadIdx.x == 0) *t.flag = f;
    if (b < t.xblocks) {
        int i = b * 256 + threadIdx.x;
        if (i < NNODE * EE)
            t.xdst[i] = f ? ((const nbf*)t.xsrc)[i] : (nbf)(((const float*)t.xsrc)[i]);
        return;
    }
    b -= t.xblocks;
    if (b < 300) {
        const int z = b / 100, rem = b % 100;
        const int by = (rem / 10) * 32, bx = (rem % 10) * 32;
        const void* src = (z == 0) ? t.tsrc0 : (z == 1) ? t.tsrc1 : t.tsrc2;
        nbf* dst = t.tdst + (size_t)z * EE * EE;
        const int tx = threadIdx.x & 31, ty = threadIdx.x >> 5;
        #pragma unroll
        for (int i = 0; i < 4; ++i) {
            const int r = by + ty + i * 8;
            float v = f ? (float)(((const nbf*)src)[(long)r * EE + bx + tx])
                        : ((const float*)src)[(long)r * EE + bx + tx];
            tile[ty + i * 8][tx] = (nbf)v;
        }
        __syncthreads();
        #pragma unroll
        for (int i = 0; i < 4; ++i) {
            const int r = bx + ty + i * 8;
            dst[(long)r * EE + by + tx] = tile[tx][ty + i * 8];
        }
        return;
    }
    b -= 300;
    int s = 0;
    while (s < NSEG - 1 && b >= t.seg_blocks[s]) { b -= t.seg_blocks[s]; ++s; }
    int i = b * 256 + threadIdx.x;
    if (i >= t.seg_n[s]) return;
    float v = f ? (float)(((const nbf*)t.seg_src[s])[i]) : ((const float*)t.seg_src[s])[i];
    if (t.seg_tobf[s]) ((nbf*)t.seg_dst[s])[i] = (nbf)v;
    else               ((float*)t.seg_dst[s])[i] = v;
}

__device__ __forceinline__ void stor(float* p, float v) { *p = v; }
__device__ __forceinline__ void stor(bf16* p, float v) { *p = __float2bfloat16(v); }

// ---------------------------------------------------------------------------
// MFMA bf16 GEMM: C[M,N] = A[M,K] @ Bt[N,K]^T + bias. 128x128 tile, BK=32.
// Full-tile fast path (uniform branch).
// ---------------------------------------------------------------------------
template<typename OT>
__global__ __launch_bounds__(256) void gemm_mfma(const nbf* __restrict__ A, int lda,
        const nbf* __restrict__ Bt, int ldb, const float* __restrict__ bias,
        OT* __restrict__ C, int ldc, int M, int Nn, int K)
{
    __shared__ __align__(16) nbf As[128][40];
    __shared__ __align__(16) nbf Bs[128][40];
    const int tid = threadIdx.x;
    const int lane = tid & 63, wave = tid >> 6;
    const int wr = (wave >> 1) * 64, wc = (wave & 1) * 64;
    const int m0 = blockIdx.y * 128, n0 = blockIdx.x * 128;
    const int lr = lane & 15, lq = lane >> 4;
    const bool full = (m0 + 128 <= M) && (n0 + 128 <= Nn);
    f32x4 acc[4][4];
    #pragma unroll
    for (int i = 0; i < 4; ++i)
        #pragma unroll
        for (int j = 0; j < 4; ++j) { acc[i][j][0]=0.f; acc[i][j][1]=0.f; acc[i][j][2]=0.f; acc[i][j][3]=0.f; }

    for (int k0 = 0; k0 < K; k0 += 32) {
        if (full) {
            #pragma unroll
            for (int v = tid; v < 512; v += 256) {
                const int row = v >> 2, cv = (v & 3) << 3;
                const int gk = k0 + cv;
                *(bf16x8*)&As[row][cv] = *(const bf16x8*)(A + (long)(m0 + row) * lda + gk);
                *(bf16x8*)&Bs[row][cv] = *(const bf16x8*)(Bt + (long)(n0 + row) * ldb + gk);
            }
        } else {
            #pragma unroll
            for (int v = tid; v < 512; v += 256) {
                const int row = v >> 2, cv = (v & 3) << 3;
                const int gk = k0 + cv;
                {
                    const int gm = m0 + row;
                    bf16x8 val;
                    if (gm < M && gk + 8 <= K) {
                        val = *(const bf16x8*)(A + (long)gm * lda + gk);
                    } else {
                        union { bf16x8 v8; nbf e[8]; } u;
                        #pragma unroll
                        for (int j = 0; j < 8; ++j) {
                            float x = (gm < M && gk + j < K) ? (float)A[(long)gm * lda + gk + j] : 0.f;
                            u.e[j] = (nbf)x;
                        }
                        val = u.v8;
                    }
                    *(bf16x8*)&As[row][cv] = val;
                }
                {
                    const int gn = n0 + row;
                    bf16x8 val;
                    if (gn < Nn && gk + 8 <= K) {
                        val = *(const bf16x8*)(Bt + (long)gn * ldb + gk);
                    } else {
                        union { bf16x8 v8; nbf e[8]; } u;
                        #pragma unroll
                        for (int j = 0; j < 8; ++j) {
                            float x = (gn < Nn && gk + j < K) ? (float)Bt[(long)gn * ldb + gk + j] : 0.f;
                            u.e[j] = (nbf)x;
                        }
                        val = u.v8;
                    }
                    *(bf16x8*)&Bs[row][cv] = val;
                }
            }
        }
        __syncthreads();
        bf16x8 af[4], bfv[4];
        #pragma unroll
        for (int i = 0; i < 4; ++i) af[i] = *(const bf16x8*)&As[wr + i * 16 + lr][lq * 8];
        #pragma unroll
        for (int j = 0; j < 4; ++j) bfv[j] = *(const bf16x8*)&Bs[wc + j * 16 + lr][lq * 8];
        #pragma unroll
        for (int i = 0; i < 4; ++i)
            #pragma unroll
            for (int j = 0; j < 4; ++j)
                acc[i][j] = __builtin_amdgcn_mfma_f32_16x16x32_bf16(af[i], bfv[j], acc[i][j], 0, 0, 0);
        __syncthreads();
    }
    #pragma unroll
    for (int i = 0; i < 4; ++i) {
        #pragma unroll
        for (int j = 0; j < 4; ++j) {
            const int gn = n0 + wc + j * 16 + lr;
            if (gn >= Nn) continue;
            const float bv = bias ? bias[gn] : 0.f;
            #pragma unroll
            for (int r = 0; r < 4; ++r) {
                const int gm = m0 + wr + i * 16 + lq * 4 + r;
                if (gm < M) stor(&C[(long)gm * ldc + gn], acc[i][j][r] + bv);
            }
        }
    }
}

// ---------------------------------------------------------------------------
// Batched 320^3 bf16 GEMMs + (z==11) bias/bfin/WfinT tasks. grid (3,3,12).
// ---------------------------------------------------------------------------
#define NJOB 11
struct JobTab {
    const nbf* A[NJOB];
    const nbf* B[NJOB];
    nbf*       C[NJOB];
};

__global__ __launch_bounds__(256) void gemm_mfma_jobs(JobTab jt,
        const float* __restrict__ qkvw_fin_f, const float* __restrict__ qkvb_fin_f,
        const float* __restrict__ ob_in_f, const float* __restrict__ ob_out_f,
        const float* __restrict__ ob_fin_f, const float* __restrict__ W_f,
        const float* __restrict__ ow_fin_f,
        float* __restrict__ bqc_in, float* __restrict__ bfin,
        float* __restrict__ WfinT_f, nbf* __restrict__ Kcat, nbf* __restrict__ VcatN)
{
    const int tid = threadIdx.x;
    if (blockIdx.z == NJOB) {
        const int t9 = blockIdx.y * 3 + blockIdx.x;   // 0..8
        if (t9 < 5) {
            const float* ob = (t9 == 2 || t9 == 4) ? ob_out_f : ob_in_f;
            const int off = (t9 == 0) ? 0 : (t9 <= 2) ? 320 : 640;
            for (int bb = tid; bb < EE; bb += 256) {
                float acc = qkvb_fin_f[off + bb];
                const float* wr = qkvw_fin_f + (long)(off + bb) * EE;
                for (int e = 0; e < EE; ++e) acc += ob[e] * wr[e];
                if (t9 == 0)      bqc_in[bb] = acc;
                else if (t9 == 1) Kcat[(long)640 * EE + bb] = (nbf)acc;
                else if (t9 == 2) Kcat[(long)641 * EE + bb] = (nbf)acc;
                else if (t9 == 3) VcatN[(long)640 * EE + bb] = (nbf)acc;
                else              VcatN[(long)641 * EE + bb] = (nbf)acc;
            }
        } else if (t9 == 5) {
            for (int j = tid; j < OUTD; j += 256) {
                float acc = 0.f;
                for (int e = 0; e < EE; ++e) acc += ob_fin_f[e] * W_f[e * OUTD + j];
                bfin[j] = acc;
            }
        } else if (t9 == 6) {
            // WfinT[j][e] = sum_a W[a][j] * fin_o_w[a][e]
            for (int v = tid; v < OUTD * EE; v += 256) {
                const int j = v / EE, e = v % EE;
                float acc = 0.f;
                for (int a = 0; a < EE; ++a)
                    acc += W_f[a * OUTD + j] * ow_fin_f[(long)a * EE + e];
                WfinT_f[v] = acc;
            }
        }
        return;
    }
    const nbf* A  = jt.A[blockIdx.z];
    const nbf* Bt = jt.B[blockIdx.z];
    nbf* C        = jt.C[blockIdx.z];
    __shared__ __align__(16) nbf As[128][40];
    __shared__ __align__(16) nbf Bs[128][40];
    const int lane = tid & 63, wave = tid >> 6;
    const int wr = (wave >> 1) * 64, wc = (wave & 1) * 64;
    const int m0 = blockIdx.y * 128, n0 = blockIdx.x * 128;
    const int lr = lane & 15, lq = lane >> 4;
    f32x4 acc[4][4];
    #pragma unroll
    for (int i = 0; i < 4; ++i)
        #pragma unroll
        for (int j = 0; j < 4; ++j) { acc[i][j][0]=0.f; acc[i][j][1]=0.f; acc[i][j][2]=0.f; acc[i][j][3]=0.f; }
    for (int k0 = 0; k0 < EE; k0 += 32) {
        #pragma unroll
        for (int v = tid; v < 512; v += 256) {
            const int row = v >> 2, cv = (v & 3) << 3;
            const int gk = k0 + cv;
            const int gm = m0 + row, gn = n0 + row;
            bf16x8 va = {}, vb = {};
            if (gm < EE) va = *(const bf16x8*)(A + (long)gm * EE + gk);
            if (gn < EE) vb = *(const bf16x8*)(Bt + (long)gn * EE + gk);
            *(bf16x8*)&As[row][cv] = va;
            *(bf16x8*)&Bs[row][cv] = vb;
        }
        __syncthreads();
        bf16x8 af[4], bfv[4];
        #pragma unroll
        for (int i = 0; i < 4; ++i) af[i] = *(const bf16x8*)&As[wr + i * 16 + lr][lq * 8];
        #pragma unroll
        for (int j = 0; j < 4; ++j) bfv[j] = *(const bf16x8*)&Bs[wc + j * 16 + lr][lq * 8];
        #pragma unroll
        for (int i = 0; i < 4; ++i)
            #pragma unroll
            for (int j = 0; j < 4; ++j)
                acc[i][j] = __builtin_amdgcn_mfma_f32_16x16x32_bf16(af[i], bfv[j], acc[i][j], 0, 0, 0);
        __syncthreads();
    }
    #pragma unroll
    for (int i = 0; i < 4; ++i)
        #pragma unroll
        for (int j = 0; j < 4; ++j) {
            const int gn = n0 + wc + j * 16 + lr;
            if (gn >= EE) continue;
            #pragma unroll
            for (int r = 0; r < 4; ++r) {
                const int gm = m0 + wr + i * 16 + lq * 4 + r;
                if (gm < EE) C[(long)gm * EE + gn] = (nbf)acc[i][j][r];
            }
        }
}

// ---------------------------------------------------------------------------
// finalize (23 blocks): 0..17 M2T tiles; 18..20 bT; 21..22 Ut(+WWTa) per dir.
// ---------------------------------------------------------------------------
__global__ __launch_bounds__(256) void finalize_kernel(
        const nbf* __restrict__ Kcat, const nbf* __restrict__ Qc,
        const float* __restrict__ bqc, const nbf* __restrict__ VcatN,
        const float* __restrict__ WfinT_f,
        nbf* __restrict__ M2T, float* __restrict__ bT,
        nbf* __restrict__ Ut, float* __restrict__ WWTa)
{
    __shared__ __align__(16) char smem[40960];
    const int b = blockIdx.x;
    const int tid = threadIdx.x;
    if (b < 18) {
        // M2T[642][320] = Kcat @ Qc^T
        nbf (*As)[40] = (nbf(*)[40])smem;
        nbf (*Bs)[40] = (nbf(*)[40])(smem + 10240);
        const int lane = tid & 63, wave = tid >> 6;
        const int wr = (wave >> 1) * 64, wc = (wave & 1) * 64;
        const int m0 = (b / 3) * 128, n0 = (b % 3) * 128;
        const int lr = lane & 15, lq = lane >> 4;
        f32x4 acc[4][4];
        #pragma unroll
        for (int i = 0; i < 4; ++i)
            #pragma unroll
            for (int j = 0; j < 4; ++j) { acc[i][j][0]=0.f; acc[i][j][1]=0.f; acc[i][j][2]=0.f; acc[i][j][3]=0.f; }
        for (int k0 = 0; k0 < EE; k0 += 32) {
            #pragma unroll
            for (int v = tid; v < 512; v += 256) {
                const int row = v >> 2, cv = (v & 3) << 3;
                const int gk = k0 + cv;
                const int gm = m0 + row, gn = n0 + row;
                bf16x8 va = {}, vb = {};
                if (gm < KF) va = *(const bf16x8*)(Kcat + (long)gm * EE + gk);
                if (gn < EE) vb = *(const bf16x8*)(Qc + (long)gn * EE + gk);
                *(bf16x8*)&As[row][cv] = va;
                *(bf16x8*)&Bs[row][cv] = vb;
            }
            __syncthreads();
            bf16x8 af[4], bfv[4];
            #pragma unroll
            for (int i = 0; i < 4; ++i) af[i] = *(const bf16x8*)&As[wr + i * 16 + lr][lq * 8];
            #pragma unroll
            for (int j = 0; j < 4; ++j) bfv[j] = *(const bf16x8*)&Bs[wc + j * 16 + lr][lq * 8];
            #pragma unroll
            for (int i = 0; i < 4; ++i)
                #pragma unroll
                for (int j = 0; j < 4; ++j)
                    acc[i][j] = __builtin_amdgcn_mfma_f32_16x16x32_bf16(af[i], bfv[j], acc[i][j], 0, 0, 0);
            __syncthreads();
        }
        #pragma unroll
        for (int i = 0; i < 4; ++i)
            #pragma unroll
            for (int j = 0; j < 4; ++j) {
                const int gn = n0 + wc + j * 16 + lr;
                if (gn >= EE) continue;
                #pragma unroll
                for (int r = 0; r < 4; ++r) {
                    const int gm = m0 + wr + i * 16 + lq * 4 + r;
                    if (gm < KF) M2T[(long)gm * EE + gn] = (nbf)acc[i][j][r];
                }
            }
        return;
    }
    if (b < 21) {
        const int c = (b - 18) * 256 + tid;
        if (c < KF) {
            const nbf* kr = Kcat + (long)c * EE;
            float acc = 0.f;
            for (int e = 0; e < EE; ++e) acc += bqc[e] * (float)kr[e];
            bT[c] = acc;
        }
        return;
    }
    // region C: Ut rows for dir d + WWTa column d
    const int d = b - 21;
    float (*Wf)[EE] = (float(*)[EE])smem;       // 30x320 f32 = 38.4 KB
    for (int v = tid; v < OUTD * EE; v += 256) Wf[v / EE][v % EE] = WfinT_f[v];
    __syncthreads();
    if (tid < OUTD) {
        const nbf* vr = VcatN + (long)(640 + d) * EE;
        float acc = 0.f;
        for (int e = 0; e < EE; ++e) acc += Wf[tid][e] * (float)vr[e];
        WWTa[tid * 2 + d] = acc;
    }
    for (int v = tid; v < 2 * EE; v += 256)
        Ut[(long)(d * 32 + 30 + v / EE) * EE + (v % EE)] = (nbf)0.f;
    for (int e = tid; e < EE; e += 256) {
        const nbf* vrow = VcatN + (long)(d * 320 + e) * EE;
        float acc[OUTD];
        #pragma unroll
        for (int j = 0; j < OUTD; ++j) acc[j] = 0.f;
        for (int a = 0; a < EE; ++a) {
            const float v = (float)vrow[a];
            #pragma unroll
            for (int j = 0; j < OUTD; ++j) acc[j] += Wf[j][a] * v;
        }
        for (int j = 0; j < OUTD; ++j)
            Ut[(long)(d * 32 + j) * EE + e] = (nbf)acc[j];
    }
}

// ---------------------------------------------------------------------------
// row0: per-node single-query in-dir attention -> Orow0[node][320] (bf16)
// ---------------------------------------------------------------------------
__global__ __launch_bounds__(256) void row0_kernel(const nbf* __restrict__ P,
        const int* __restrict__ in_idx, nbf* __restrict__ Orow0)
{
    const int tid = threadIdx.x, lane = tid & 63, wave = tid >> 6;
    const int node = blockIdx.x * 4 + wave;
    __shared__ float a_sh[4][16];
    __shared__ int srcs_sh[4][16];
    const int m = lane & 15, q4 = lane >> 4;
    const int src = (m == 0) ? node : in_idx[node * DDEG + m - 1];
    if (q4 == 0) srcs_sh[wave][m] = src;
    const nbf* qrow = P + (long)node * PCOLS;
    const nbf* krow = P + (long)src * PCOLS + 320;
    #pragma unroll
    for (int h = 0; h < NH; ++h) {
        float s = 0.f;
        bf16x8 q1 = *(const bf16x8*)(qrow + h * 64 + q4 * 16);
        bf16x8 q2 = *(const bf16x8*)(qrow + h * 64 + q4 * 16 + 8);
        bf16x8 k1 = *(const bf16x8*)(krow + h * 64 + q4 * 16);
        bf16x8 k2 = *(const bf16x8*)(krow + h * 64 + q4 * 16 + 8);
        #pragma unroll
        for (int j = 0; j < 8; ++j)
            s += (float)q1[j] * (float)k1[j] + (float)q2[j] * (float)k2[j];
        s += __shfl_xor(s, 16);
        s += __shfl_xor(s, 32);
        s *= 0.125f;
        float mxv = s;
        #pragma unroll
        for (int msk = 8; msk >= 1; msk >>= 1) mxv = fmaxf(mxv, __shfl_xor(mxv, msk));
        float e = __expf(s - mxv);
        float es = e;
        #pragma unroll
        for (int msk = 8; msk >= 1; msk >>= 1) es += __shfl_xor(es, msk);
        if (q4 == 0) a_sh[wave][m] = e / es;
        float o = 0.f;
        #pragma unroll
        for (int mm = 0; mm < 16; ++mm)
            o += a_sh[wave][mm] * (float)P[(long)srcs_sh[wave][mm] * PCOLS + 640 + h * 64 + lane];
        Orow0[(long)node * EE + h * 64 + lane] = (nbf)o;
    }
}

// ---------------------------------------------------------------------------
// attn_y: per (node,dir) block (320 thr = 5 waves = heads). Y B-frags
// (Ut + smuggled T row) prefetched at kernel top.
// ---------------------------------------------------------------------------
__global__ __launch_bounds__(320) void attn_y_kernel(const nbf* __restrict__ P,
        const int* __restrict__ in_idx, const int* __restrict__ out_idx,
        const nbf* __restrict__ Tb, const nbf* __restrict__ Ut,
        float* __restrict__ Ygl, int node_base)
{
    const int bx = blockIdx.x;
    const int lnode = bx >> 1, d = bx & 1;
    const int node = node_base + lnode;
    const int tid = threadIdx.x;
    const int lane = tid & 63, wave = tid >> 6;      // wave == head
    __shared__ __align__(16) nbf v_s[16][328];       // V, then O overlay per slab
    __shared__ __align__(16) nbf p_s[NH][16][16];
    __shared__ float Yp[NH][16][32];
    const int* idx = d ? out_idx : in_idx;
    const long coloff = (long)d * 960;
    const int lr = lane & 15, lq = lane >> 4;
    // ---- prefetch Y B-frags (independent of everything) ----
    const nbf* Utd = Ut + (long)d * 32 * EE;
    const nbf* TbRow = Tb + (long)node * TSTB + (long)d * 320;
    bf16x8 yb[2][2];
    #pragma unroll
    for (int c = 0; c < 2; ++c)
        #pragma unroll
        for (int nt = 0; nt < 2; ++nt) {
            const int kk = wave * 64 + c * 32 + lq * 8;
            const int row = nt * 16 + lr;
            yb[c][nt] = *(const bf16x8*)((row == 31) ? (TbRow + kk)
                                                     : (Utd + (long)row * EE + kk));
        }
    // ---- stage V ----
    #pragma unroll
    for (int v = tid; v < 640; v += 320) {
        const int row = v / 40, c8 = (v % 40) * 8;
        const int src = (row == 0) ? node : idx[node * DDEG + row - 1];
        *(bf16x8*)&v_s[row][c8] = *(const bf16x8*)(P + (long)src * PCOLS + coloff + 640 + c8);
    }
    // ---- Q/K direct from global; QK^T overlaps V staging ----
    const int msrc = (lr == 0) ? node : idx[node * DDEG + lr - 1];
    const nbf* prow = P + (long)msrc * PCOLS + coloff;
    f32x4 sc = {0.f, 0.f, 0.f, 0.f};
    #pragma unroll
    for (int c = 0; c < 2; ++c) {
        bf16x8 aq = *(const bf16x8*)(prow + wave * 64 + c * 32 + lq * 8);
        bf16x8 bk = *(const bf16x8*)(prow + 320 + wave * 64 + c * 32 + lq * 8);
        sc = __builtin_amdgcn_mfma_f32_16x16x32_bf16(aq, bk, sc, 0, 0, 0);
    }
    // ---- softmax over m (= lane&15) ----
    float pr[4], mx4[4], sm4[4];
    #pragma unroll
    for (int r = 0; r < 4; ++r) { pr[r] = sc[r] * 0.125f; mx4[r] = pr[r]; }
    #pragma unroll
    for (int msk = 8; msk >= 1; msk >>= 1)
        #pragma unroll
        for (int r = 0; r < 4; ++r) mx4[r] = fmaxf(mx4[r], __shfl_xor(mx4[r], msk));
    #pragma unroll
    for (int r = 0; r < 4; ++r) { pr[r] = __expf(pr[r] - mx4[r]); sm4[r] = pr[r]; }
    #pragma unroll
    for (int msk = 8; msk >= 1; msk >>= 1)
        #pragma unroll
        for (int r = 0; r < 4; ++r) sm4[r] += __shfl_xor(sm4[r], msk);
    #pragma unroll
    for (int r = 0; r < 4; ++r) p_s[wave][lq * 4 + r][lr] = (nbf)(pr[r] / sm4[r]);
    union { bf16x8 v8; nbf e[8]; } pf;
    #pragma unroll
    for (int j = 0; j < 8; ++j) pf.e[j] = (nbf)0.f;
    if (lq < 2) pf.v8 = *(const bf16x8*)&p_s[wave][lr][lq * 8];
    __syncthreads();   // v_s ready
    // ---- AV; O overlaid into this wave's own (consumed) V col-slab ----
    #pragma unroll
    for (int t = 0; t < 4; ++t) {
        const int e0 = wave * 64 + t * 16;
        union { bf16x8 v8; nbf e[8]; } af;
        #pragma unroll
        for (int j = 0; j < 8; ++j) af.e[j] = (nbf)0.f;
        if (lq < 2) {
            #pragma unroll
            for (int j = 0; j < 8; ++j) af.e[j] = v_s[lq * 8 + j][e0 + lr];
        }
        f32x4 ov = {0.f, 0.f, 0.f, 0.f};
        ov = __builtin_amdgcn_mfma_f32_16x16x32_bf16(af.v8, pf.v8, ov, 0, 0, 0);
        union { unsigned long long u; nbf e[4]; } o4;
        #pragma unroll
        for (int r = 0; r < 4; ++r) o4.e[r] = (nbf)ov[r];
        *(unsigned long long*)&v_s[lr][e0 + lq * 4] = o4.u;   // O[l=lr][..]
    }
    // ---- Y partials over this wave's 64-e slab (same-wave LDS ordering) ----
    f32x4 yacc[2];
    yacc[0][0]=0.f; yacc[0][1]=0.f; yacc[0][2]=0.f; yacc[0][3]=0.f;
    yacc[1][0]=0.f; yacc[1][1]=0.f; yacc[1][2]=0.f; yacc[1][3]=0.f;
    const int e0w = wave * 64;
    #pragma unroll
    for (int c = 0; c < 2; ++c) {
        const int kk = e0w + c * 32 + lq * 8;
        bf16x8 afy = *(const bf16x8*)&v_s[lr][kk];
        #pragma unroll
        for (int nt = 0; nt < 2; ++nt)
            yacc[nt] = __builtin_amdgcn_mfma_f32_16x16x32_bf16(afy, yb[c][nt], yacc[nt], 0, 0, 0);
    }
    #pragma unroll
    for (int nt = 0; nt < 2; ++nt)
        #pragma unroll
        for (int r = 0; r < 4; ++r)
            Yp[wave][lq * 4 + r][nt * 16 + lr] = yacc[nt][r];
    __syncthreads();
    // ---- cross-wave reduce + coalesced 2KB store ----
    float* yout = Ygl + (long)(lnode * 2 + d) * 512;
    for (int v = tid; v < 512; v += 320) {
        float sme = 0.f;
        #pragma unroll
        for (int w = 0; w < NH; ++w) sme += Yp[w][v >> 5][v & 31];
        yout[v] = sme;
    }
}

// ---------------------------------------------------------------------------
// combine: 4 nodes/block, one wave per node.
// ---------------------------------------------------------------------------
__global__ __launch_bounds__(256) void combine_kernel(const float* __restrict__ Ygl,
        const nbf* __restrict__ Tb, const float* __restrict__ WWTa,
        const float* __restrict__ bfin, void* __restrict__ out,
        long obase, int cnt, const int* __restrict__ flag)
{
    const int tid = threadIdx.x, lane = tid & 63, wave = tid >> 6;
    const int node = blockIdx.x * 4 + wave;
    const int nodec = (node < cnt) ? node : (cnt - 1);
    __shared__ float Yl[4][1024];
    __shared__ float sf[4][32];
    const float* ysrc = Ygl + (long)nodec * 1024;
    #pragma unroll
    for (int v = lane; v < 1024; v += 64) Yl[wave][v] = ysrc[v];
    if (lane < 32) {
        const int d = lane >> 4, m = lane & 15;
        sf[wave][lane] = (Yl[wave][d * 512 + m * 32 + 31]
                          + (float)Tb[(long)nodec * TSTB + 640 + d]) * 0.05590169943749474f;
    }
    float mx = -1e30f;
    #pragma unroll 4
    for (int m = 0; m < 32; ++m) mx = fmaxf(mx, sf[wave][m]);
    float esum = 0.f, a_in = 0.f, a_out = 0.f;
    #pragma unroll 4
    for (int m = 0; m < 32; ++m) {
        float e = __expf(sf[wave][m] - mx);
        esum += e;
        if (m < 16) a_in += e; else a_out += e;
    }
    const float inv = 1.f / esum;
    a_in *= inv; a_out *= inv;
    const int j = lane;
    if (j < OUTD && node < cnt) {
        float acc = 0.f;
        #pragma unroll 4
        for (int dm = 0; dm < 32; ++dm) {
            const int d = dm >> 4, m = dm & 15;
            float a = __expf(sf[wave][dm] - mx) * inv;
            acc += a * Yl[wave][d * 512 + m * 32 + j];
        }
        float r = acc + a_in * WWTa[j * 2] + a_out * WWTa[j * 2 + 1] + bfin[j];
        r = r > 0.f ? r : expm1f(r);
        if (*flag) ((bf16*)out)[obase + (long)node * OUTD + j] = __float2bfloat16(r);
        else       ((float*)out)[obase + (long)node * OUTD + j] = r;
    }
}

// ---------------------------------------------------------------------------
extern "C" void kernel_launch(void* const* d_in, const int* in_sizes, int n_in,
                              void* d_out, int out_size, void* d_ws, size_t ws_size,
                              hipStream_t stream)
{
    const int* in_idx  = (const int*)d_in[1];
    const int* out_idx = (const int*)d_in[2];

    char* p = (char*)d_ws;
    auto alloc = [&](size_t bytes) { char* r = p; p += (bytes + 255) & ~(size_t)255; return r; };
    const size_t EE2 = (size_t)EE * EE;
    int*   flag       = (int*)alloc(256);
    nbf*   X_bf       = (nbf*)alloc((size_t)NNODE * EE * 2);
    nbf*   qkvw6_bf   = (nbf*)alloc(6 * EE2 * 2);
    nbf*   Wg6_bf     = (nbf*)alloc(6 * EE2 * 2);
    nbf*   qkvw_fin_bf= (nbf*)alloc(3 * EE2 * 2);
    nbf*   owT        = (nbf*)alloc(3 * EE2 * 2);
    float* qkvw_fin_f = (float*)alloc(3 * EE2 * 4);
    float* qkvb_fin_f = (float*)alloc(3 * EE * 4);
    float* bcat       = (float*)alloc(PCOLS * 4);
    float* ob_in_f    = (float*)alloc(EE * 4);
    float* ob_out_f   = (float*)alloc(EE * 4);
    float* ob_fin_f   = (float*)alloc(EE * 4);
    float* W_f        = (float*)alloc((size_t)EE * OUTD * 4);
    float* ow_fin_f   = (float*)alloc(EE2 * 4);
    // composed
    nbf*   AcatT  = (nbf*)alloc((size_t)PCOLS * EE * 2);
    nbf*   Qc_bf  = (nbf*)alloc(EE2 * 2);
    nbf*   Kcat   = (nbf*)alloc((size_t)KF * EE * 2);
    float* bqc_in = (float*)alloc(EE * 4);
    nbf*   M2T    = (nbf*)alloc((size_t)KF * EE * 2);
    float* bT     = (float*)alloc(KF * 4);
    nbf*   VcatN  = (nbf*)alloc((size_t)KF * EE * 2);
    float* WfinT_f= (float*)alloc((size_t)OUTD * EE * 4);
    float* WWTa   = (float*)alloc(64 * 4);
    float* bfin   = (float*)alloc(64 * 4);
    nbf*   Ut     = (nbf*)alloc((size_t)64 * EE * 2);
    nbf*   P      = (nbf*)alloc((size_t)NNODE * PCOLS * 2);
    nbf*   Orow0  = (nbf*)alloc((size_t)NNODE * EE * 2);
    nbf*   Tb     = (nbf*)alloc((size_t)NNODE * TSTB * 2);
    size_t fixed = (size_t)(p - (char*)d_ws);

    const size_t per_node = 1024 * 4;
    size_t avail = (ws_size > fixed + 65536) ? (ws_size - fixed - 65536) : 0;
    long chunk_l = (long)(avail / per_node);
    chunk_l = (chunk_l / 4) * 4;
    int chunk = (chunk_l > NNODE) ? NNODE : (chunk_l < 4 ? 4 : (int)chunk_l);
    float* Ygl = (float*)alloc((size_t)chunk * 1024 * 4);

    dim3 blk(256);
    // ---- prep: detect + all converts + transposes in ONE launch ----
    PrepTab pt;
    pt.xsrc = d_in[0]; pt.xdst = X_bf; pt.xblocks = (NNODE * EE + 255) / 256;
    pt.tsrc0 = d_in[8]; pt.tsrc1 = d_in[15]; pt.tsrc2 = d_in[19]; pt.tdst = owT;
    pt.flag = flag;
    int s = 0;
    auto seg = [&](const void* src, void* dst, int n, int tobf) {
        pt.seg_src[s] = src; pt.seg_dst[s] = dst; pt.seg_n[s] = n;
        pt.seg_tobf[s] = tobf; pt.seg_blocks[s] = (n + 255) / 256; ++s;
    };
    seg(d_in[6],  qkvw6_bf,           (int)(3 * EE2), 1);
    seg(d_in[13], qkvw6_bf + 3 * EE2, (int)(3 * EE2), 1);
    seg(d_in[3],  Wg6_bf + 0 * EE2, (int)EE2, 1);
    seg(d_in[4],  Wg6_bf + 1 * EE2, (int)EE2, 1);
    seg(d_in[5],  Wg6_bf + 2 * EE2, (int)EE2, 1);
    seg(d_in[10], Wg6_bf + 3 * EE2, (int)EE2, 1);
    seg(d_in[11], Wg6_bf + 4 * EE2, (int)EE2, 1);
    seg(d_in[12], Wg6_bf + 5 * EE2, (int)EE2, 1);
    seg(d_in[17], qkvw_fin_bf, (int)(3 * EE2), 1);
    seg(d_in[17], qkvw_fin_f,  (int)(3 * EE2), 0);
    seg(d_in[18], qkvb_fin_f, 3 * EE, 0);
    seg(d_in[7],  bcat,       3 * EE, 0);
    seg(d_in[14], bcat + 960, 3 * EE, 0);
    seg(d_in[9],  ob_in_f,  EE, 0);
    seg(d_in[16], ob_out_f, EE, 0);
    seg(d_in[20], ob_fin_f, EE, 0);
    seg(d_in[21], W_f, EE * OUTD, 0);
    seg(d_in[19], ow_fin_f, (int)EE2, 0);
    int total_blocks = pt.xblocks + 300;
    for (int i = 0; i < NSEG; ++i) total_blocks += pt.seg_blocks[i];
    prep_kernel<<<total_blocks, blk, 0, stream>>>(pt);

    // ---- compose GEMMs + bias/bfin/WfinT tasks in ONE launch ----
    JobTab jt;
    for (int g = 0; g < 6; ++g) {
        jt.A[g] = qkvw6_bf + (size_t)g * EE2;
        jt.B[g] = Wg6_bf + (size_t)g * EE2;
        jt.C[g] = AcatT + (size_t)g * EE2;
    }
    jt.A[6] = owT;        jt.B[6] = qkvw_fin_bf;                      jt.C[6] = Qc_bf;
    jt.A[7] = owT;        jt.B[7] = qkvw_fin_bf + (size_t)320 * EE;   jt.C[7] = Kcat;
    jt.A[8] = owT + EE2;  jt.B[8] = qkvw_fin_bf + (size_t)320 * EE;   jt.C[8] = Kcat + (size_t)320 * EE;
    jt.A[9] = owT;        jt.B[9] = qkvw_fin_bf + (size_t)640 * EE;   jt.C[9] = VcatN;
    jt.A[10]= owT + EE2;  jt.B[10]= qkvw_fin_bf + (size_t)640 * EE;   jt.C[10]= VcatN + (size_t)320 * EE;
    gemm_mfma_jobs<<<dim3(3, 3, NJOB + 1), blk, 0, stream>>>(jt,
        qkvw_fin_f, qkvb_fin_f, ob_in_f, ob_out_f, ob_fin_f, W_f, ow_fin_f,
        bqc_in, bfin, WfinT_f, Kcat, VcatN);

    // ---- P = X @ Acat + bcat ----
    gemm_mfma<bf16><<<dim3(PCOLS / 128, (NNODE + 127) / 128), blk, 0, stream>>>(
        X_bf, EE, AcatT, EE, bcat, (bf16*)P, PCOLS, NNODE, PCOLS, EE);

    // ---- M2T + bT + Ut + WWTa in ONE launch ----
    finalize_kernel<<<23, blk, 0, stream>>>(Kcat, Qc_bf, bqc_in, VcatN, WfinT_f,
                                            M2T, bT, Ut, WWTa);

    // ---- row0 in-attention -> Orow0 ----
    row0_kernel<<<NNODE / 4, blk, 0, stream>>>(P, in_idx, Orow0);

    // ---- T = Orow0 @ M2T + bT -> bf16, padded stride TSTB ----
    gemm_mfma<bf16><<<dim3((KF + 127) / 128, (NNODE + 127) / 128), blk, 0, stream>>>(
        Orow0, EE, M2T, EE, bT, (bf16*)Tb, TSTB, NNODE, KF, EE);

    // ---- per-node pipeline (chunked over Y buffer) ----
    for (int base = 0; base < NNODE; base += chunk) {
        int cnt = (NNODE - base < chunk) ? (NNODE - base) : chunk;
        attn_y_kernel<<<2 * cnt, dim3(320), 0, stream>>>(
            P, in_idx, out_idx, Tb, Ut, Ygl, base);
        combine_kernel<<<(cnt + 3) / 4, blk, 0, stream>>>(
            Ygl, Tb + (size_t)base * TSTB, WWTa, bfin, d_out, (long)base * OUTD, cnt, flag);
    }
}

// Round 13
// 556.166 us; speedup vs baseline: 1.3353x; 1.3353x over previous
//
#include <hip/hip_runtime.h>
#include <hip/hip_bf16.h>

typedef __hip_bfloat16 bf16;
typedef __bf16 nbf;
typedef nbf bf16x8 __attribute__((ext_vector_type(8)));
typedef float f32x4 __attribute__((ext_vector_type(4)));

#define NNODE 10000
#define DDEG  15
#define EE    320
#define NH    5
#define OUTD  30
#define PCOLS 1920   // 6*E : [Qin|Kin|Vin|Qout|Kout|Vout]
#define KF    642    // 2*E + 2 (alpha columns)
#define TSTB  648    // padded bf16 T row stride (16B-aligned rows)

// ---------------------------------------------------------------------------
// prep: ONE launch = inline dtype detect (per-block, deterministic) +
// X convert + 3 transposes + 18 segment converts. Block ranges by blockIdx.
// ---------------------------------------------------------------------------
#define NSEG 18
struct PrepTab {
    const void* seg_src[NSEG];
    void*       seg_dst[NSEG];
    int         seg_n[NSEG];
    int         seg_tobf[NSEG];
    int         seg_blocks[NSEG];
    const void* xsrc; nbf* xdst; int xblocks;
    const void* tsrc0; const void* tsrc1; const void* tsrc2; nbf* tdst;
    int* flag;
};

__global__ __launch_bounds__(256) void prep_kernel(PrepTab t)
{
    __shared__ int cnt_s;
    __shared__ __align__(16) nbf tile[32][33];
    if (threadIdx.x == 0) cnt_s = 0;
    __syncthreads();
    {
        const unsigned int* Xw = (const unsigned int*)t.xsrc;
        int local = 0;
        for (int i = threadIdx.x; i < 1024; i += 256) {
            unsigned int lo = Xw[i] & 0xFFFFu;
            int e = (int)((lo >> 7) & 0xFFu);
            if (e >= 100 && e <= 140) local++;
        }
        atomicAdd(&cnt_s, local);
    }
    __syncthreads();
    const int f = cnt_s > 512;
    int b = blockIdx.x;
    if (b == 0 && threadIdx.x == 0) *t.flag = f;
    if (b < t.xblocks) {
        int i = b * 256 + threadIdx.x;
        if (i < NNODE * EE)
            t.xdst[i] = f ? ((const nbf*)t.xsrc)[i] : (nbf)(((const float*)t.xsrc)[i]);
        return;
    }
    b -= t.xblocks;
    if (b < 300) {
        const int z = b / 100, rem = b % 100;
        const int by = (rem / 10) * 32, bx = (rem % 10) * 32;
        const void* src = (z == 0) ? t.tsrc0 : (z == 1) ? t.tsrc1 : t.tsrc2;
        nbf* dst = t.tdst + (size_t)z * EE * EE;
        const int tx = threadIdx.x & 31, ty = threadIdx.x >> 5;
        #pragma unroll
        for (int i = 0; i < 4; ++i) {
            const int r = by + ty + i * 8;
            float v = f ? (float)(((const nbf*)src)[(long)r * EE + bx + tx])
                        : ((const float*)src)[(long)r * EE + bx + tx];
            tile[ty + i * 8][tx] = (nbf)v;
        }
        __syncthreads();
        #pragma unroll
        for (int i = 0; i < 4; ++i) {
            const int r = bx + ty + i * 8;
            dst[(long)r * EE + by + tx] = tile[tx][ty + i * 8];
        }
        return;
    }
    b -= 300;
    int s = 0;
    while (s < NSEG - 1 && b >= t.seg_blocks[s]) { b -= t.seg_blocks[s]; ++s; }
    int i = b * 256 + threadIdx.x;
    if (i >= t.seg_n[s]) return;
    float v = f ? (float)(((const nbf*)t.seg_src[s])[i]) : ((const float*)t.seg_src[s])[i];
    if (t.seg_tobf[s]) ((nbf*)t.seg_dst[s])[i] = (nbf)v;
    else               ((float*)t.seg_dst[s])[i] = v;
}

__device__ __forceinline__ void stor(float* p, float v) { *p = v; }
__device__ __forceinline__ void stor(bf16* p, float v) { *p = __float2bfloat16(v); }

// ---------------------------------------------------------------------------
// VALU 64x64 GEMM (tiny WfinT compose; f32 in/out)
// ---------------------------------------------------------------------------
template<bool AT, bool BT, typename OT>
__global__ __launch_bounds__(256) void gemm_k(const float* __restrict__ A, int lda,
                       const float* __restrict__ B, int ldb,
                       const float* __restrict__ bias,
                       OT* __restrict__ C, int ldc, int M, int Nn, int K)
{
    __shared__ float As[16][65];
    __shared__ float Bs[16][65];
    const int tid = threadIdx.x;
    const int tx = tid & 15, ty = tid >> 4;
    const int n0 = blockIdx.x * 64, m0 = blockIdx.y * 64;
    float acc[4][4] = {};
    for (int k0 = 0; k0 < K; k0 += 16) {
        if constexpr (AT) {
            for (int i = tid; i < 1024; i += 256) {
                int kk = i >> 6, r = i & 63;
                int gm = m0 + r, gk = k0 + kk;
                As[kk][r] = (gm < M && gk < K) ? A[(long)gk * lda + gm] : 0.f;
            }
        } else {
            for (int i = tid; i < 1024; i += 256) {
                int r = i >> 4, kk = i & 15;
                int gm = m0 + r, gk = k0 + kk;
                As[kk][r] = (gm < M && gk < K) ? A[(long)gm * lda + gk] : 0.f;
            }
        }
        if constexpr (BT) {
            for (int i = tid; i < 1024; i += 256) {
                int r = i >> 4, kk = i & 15;
                int gn = n0 + r, gk = k0 + kk;
                Bs[kk][r] = (gn < Nn && gk < K) ? B[(long)gn * ldb + gk] : 0.f;
            }
        } else {
            for (int i = tid; i < 1024; i += 256) {
                int kk = i >> 6, c = i & 63;
                int gk = k0 + kk, gn = n0 + c;
                Bs[kk][c] = (gk < K && gn < Nn) ? B[(long)gk * ldb + gn] : 0.f;
            }
        }
        __syncthreads();
        #pragma unroll
        for (int kk = 0; kk < 16; ++kk) {
            float ra[4], rb[4];
            #pragma unroll
            for (int a = 0; a < 4; ++a) ra[a] = As[kk][ty * 4 + a];
            #pragma unroll
            for (int b = 0; b < 4; ++b) rb[b] = Bs[kk][tx * 4 + b];
            #pragma unroll
            for (int a = 0; a < 4; ++a)
                #pragma unroll
                for (int b = 0; b < 4; ++b)
                    acc[a][b] += ra[a] * rb[b];
        }
        __syncthreads();
    }
    #pragma unroll
    for (int a = 0; a < 4; ++a) {
        int gm = m0 + ty * 4 + a;
        if (gm >= M) continue;
        #pragma unroll
        for (int b = 0; b < 4; ++b) {
            int gn = n0 + tx * 4 + b;
            if (gn >= Nn) continue;
            float v = acc[a][b] + (bias ? bias[gn] : 0.f);
            stor(&C[(long)gm * ldc + gn], v);
        }
    }
}

// ---------------------------------------------------------------------------
// MFMA bf16 GEMM: C[M,N] = A[M,K] @ Bt[N,K]^T + bias. 128x128 tile, BK=32.
// Full-tile fast path (uniform branch).
// ---------------------------------------------------------------------------
template<typename OT>
__global__ __launch_bounds__(256) void gemm_mfma(const nbf* __restrict__ A, int lda,
        const nbf* __restrict__ Bt, int ldb, const float* __restrict__ bias,
        OT* __restrict__ C, int ldc, int M, int Nn, int K)
{
    __shared__ __align__(16) nbf As[128][40];
    __shared__ __align__(16) nbf Bs[128][40];
    const int tid = threadIdx.x;
    const int lane = tid & 63, wave = tid >> 6;
    const int wr = (wave >> 1) * 64, wc = (wave & 1) * 64;
    const int m0 = blockIdx.y * 128, n0 = blockIdx.x * 128;
    const int lr = lane & 15, lq = lane >> 4;
    const bool full = (m0 + 128 <= M) && (n0 + 128 <= Nn);
    f32x4 acc[4][4];
    #pragma unroll
    for (int i = 0; i < 4; ++i)
        #pragma unroll
        for (int j = 0; j < 4; ++j) { acc[i][j][0]=0.f; acc[i][j][1]=0.f; acc[i][j][2]=0.f; acc[i][j][3]=0.f; }

    for (int k0 = 0; k0 < K; k0 += 32) {
        if (full) {
            #pragma unroll
            for (int v = tid; v < 512; v += 256) {
                const int row = v >> 2, cv = (v & 3) << 3;
                const int gk = k0 + cv;
                *(bf16x8*)&As[row][cv] = *(const bf16x8*)(A + (long)(m0 + row) * lda + gk);
                *(bf16x8*)&Bs[row][cv] = *(const bf16x8*)(Bt + (long)(n0 + row) * ldb + gk);
            }
        } else {
            #pragma unroll
            for (int v = tid; v < 512; v += 256) {
                const int row = v >> 2, cv = (v & 3) << 3;
                const int gk = k0 + cv;
                {
                    const int gm = m0 + row;
                    bf16x8 val;
                    if (gm < M && gk + 8 <= K) {
                        val = *(const bf16x8*)(A + (long)gm * lda + gk);
                    } else {
                        union { bf16x8 v8; nbf e[8]; } u;
                        #pragma unroll
                        for (int j = 0; j < 8; ++j) {
                            float x = (gm < M && gk + j < K) ? (float)A[(long)gm * lda + gk + j] : 0.f;
                            u.e[j] = (nbf)x;
                        }
                        val = u.v8;
                    }
                    *(bf16x8*)&As[row][cv] = val;
                }
                {
                    const int gn = n0 + row;
                    bf16x8 val;
                    if (gn < Nn && gk + 8 <= K) {
                        val = *(const bf16x8*)(Bt + (long)gn * ldb + gk);
                    } else {
                        union { bf16x8 v8; nbf e[8]; } u;
                        #pragma unroll
                        for (int j = 0; j < 8; ++j) {
                            float x = (gn < Nn && gk + j < K) ? (float)Bt[(long)gn * ldb + gk + j] : 0.f;
                            u.e[j] = (nbf)x;
                        }
                        val = u.v8;
                    }
                    *(bf16x8*)&Bs[row][cv] = val;
                }
            }
        }
        __syncthreads();
        bf16x8 af[4], bfv[4];
        #pragma unroll
        for (int i = 0; i < 4; ++i) af[i] = *(const bf16x8*)&As[wr + i * 16 + lr][lq * 8];
        #pragma unroll
        for (int j = 0; j < 4; ++j) bfv[j] = *(const bf16x8*)&Bs[wc + j * 16 + lr][lq * 8];
        #pragma unroll
        for (int i = 0; i < 4; ++i)
            #pragma unroll
            for (int j = 0; j < 4; ++j)
                acc[i][j] = __builtin_amdgcn_mfma_f32_16x16x32_bf16(af[i], bfv[j], acc[i][j], 0, 0, 0);
        __syncthreads();
    }
    #pragma unroll
    for (int i = 0; i < 4; ++i) {
        #pragma unroll
        for (int j = 0; j < 4; ++j) {
            const int gn = n0 + wc + j * 16 + lr;
            if (gn >= Nn) continue;
            const float bv = bias ? bias[gn] : 0.f;
            #pragma unroll
            for (int r = 0; r < 4; ++r) {
                const int gm = m0 + wr + i * 16 + lq * 4 + r;
                if (gm < M) stor(&C[(long)gm * ldc + gn], acc[i][j][r] + bv);
            }
        }
    }
}

// ---------------------------------------------------------------------------
// Batched 320^3 bf16 GEMMs: C[j] = A[j] @ B[j]^T. grid (3,3,11). Pure GEMM.
// ---------------------------------------------------------------------------
#define NJOB 11
struct JobTab {
    const nbf* A[NJOB];
    const nbf* B[NJOB];
    nbf*       C[NJOB];
};

__global__ __launch_bounds__(256) void gemm_mfma_jobs(JobTab jt)
{
    const nbf* A  = jt.A[blockIdx.z];
    const nbf* Bt = jt.B[blockIdx.z];
    nbf* C        = jt.C[blockIdx.z];
    __shared__ __align__(16) nbf As[128][40];
    __shared__ __align__(16) nbf Bs[128][40];
    const int tid = threadIdx.x;
    const int lane = tid & 63, wave = tid >> 6;
    const int wr = (wave >> 1) * 64, wc = (wave & 1) * 64;
    const int m0 = blockIdx.y * 128, n0 = blockIdx.x * 128;
    const int lr = lane & 15, lq = lane >> 4;
    f32x4 acc[4][4];
    #pragma unroll
    for (int i = 0; i < 4; ++i)
        #pragma unroll
        for (int j = 0; j < 4; ++j) { acc[i][j][0]=0.f; acc[i][j][1]=0.f; acc[i][j][2]=0.f; acc[i][j][3]=0.f; }
    for (int k0 = 0; k0 < EE; k0 += 32) {
        #pragma unroll
        for (int v = tid; v < 512; v += 256) {
            const int row = v >> 2, cv = (v & 3) << 3;
            const int gk = k0 + cv;
            const int gm = m0 + row, gn = n0 + row;
            bf16x8 va = {}, vb = {};
            if (gm < EE) va = *(const bf16x8*)(A + (long)gm * EE + gk);
            if (gn < EE) vb = *(const bf16x8*)(Bt + (long)gn * EE + gk);
            *(bf16x8*)&As[row][cv] = va;
            *(bf16x8*)&Bs[row][cv] = vb;
        }
        __syncthreads();
        bf16x8 af[4], bfv[4];
        #pragma unroll
        for (int i = 0; i < 4; ++i) af[i] = *(const bf16x8*)&As[wr + i * 16 + lr][lq * 8];
        #pragma unroll
        for (int j = 0; j < 4; ++j) bfv[j] = *(const bf16x8*)&Bs[wc + j * 16 + lr][lq * 8];
        #pragma unroll
        for (int i = 0; i < 4; ++i)
            #pragma unroll
            for (int j = 0; j < 4; ++j)
                acc[i][j] = __builtin_amdgcn_mfma_f32_16x16x32_bf16(af[i], bfv[j], acc[i][j], 0, 0, 0);
        __syncthreads();
    }
    #pragma unroll
    for (int i = 0; i < 4; ++i)
        #pragma unroll
        for (int j = 0; j < 4; ++j) {
            const int gn = n0 + wc + j * 16 + lr;
            if (gn >= EE) continue;
            #pragma unroll
            for (int r = 0; r < 4; ++r) {
                const int gm = m0 + wr + i * 16 + lq * 4 + r;
                if (gm < EE) C[(long)gm * EE + gn] = (nbf)acc[i][j][r];
            }
        }
}

// ---------------------------------------------------------------------------
// merged bias compose (efficient 320-thread blocks): which 0..4, 5 -> bfin
// ---------------------------------------------------------------------------
__global__ __launch_bounds__(320) void compose_bias_bfin_kernel(
        const float* __restrict__ in_o_b, const float* __restrict__ out_o_b,
        const float* __restrict__ fin_qkv_w, const float* __restrict__ fin_qkv_b,
        const float* __restrict__ fin_o_b, const float* __restrict__ W,
        float* __restrict__ bqc_in, nbf* __restrict__ Kcat, nbf* __restrict__ VcatN,
        float* __restrict__ bfin)
{
    const int which = blockIdx.x;
    const int b = threadIdx.x;
    if (which == 5) {
        if (b >= OUTD) return;
        float acc = 0.f;
        for (int e = 0; e < EE; ++e) acc += fin_o_b[e] * W[e * OUTD + b];
        bfin[b] = acc;
        return;
    }
    const float* ob = (which == 2 || which == 4) ? out_o_b : in_o_b;
    const int off = (which == 0) ? 0 : (which <= 2) ? 320 : 640;
    float acc = fin_qkv_b[off + b];
    const float* wr = fin_qkv_w + (long)(off + b) * EE;
    for (int e = 0; e < EE; ++e) acc += ob[e] * wr[e];
    if (which == 0)      bqc_in[b] = acc;
    else if (which == 1) Kcat[(long)640 * EE + b] = (nbf)acc;
    else if (which == 2) Kcat[(long)641 * EE + b] = (nbf)acc;
    else if (which == 3) VcatN[(long)640 * EE + b] = (nbf)acc;
    else                 VcatN[(long)641 * EE + b] = (nbf)acc;
}

// ---------------------------------------------------------------------------
// finalize (23 blocks): 0..17 M2T tiles; 18..20 bT; 21..22 Ut(+WWTa) per dir.
// ---------------------------------------------------------------------------
__global__ __launch_bounds__(256) void finalize_kernel(
        const nbf* __restrict__ Kcat, const nbf* __restrict__ Qc,
        const float* __restrict__ bqc, const nbf* __restrict__ VcatN,
        const float* __restrict__ WfinT_f,
        nbf* __restrict__ M2T, float* __restrict__ bT,
        nbf* __restrict__ Ut, float* __restrict__ WWTa)
{
    __shared__ __align__(16) char smem[40960];
    const int b = blockIdx.x;
    const int tid = threadIdx.x;
    if (b < 18) {
        // M2T[642][320] = Kcat @ Qc^T
        nbf (*As)[40] = (nbf(*)[40])smem;
        nbf (*Bs)[40] = (nbf(*)[40])(smem + 10240);
        const int lane = tid & 63, wave = tid >> 6;
        const int wr = (wave >> 1) * 64, wc = (wave & 1) * 64;
        const int m0 = (b / 3) * 128, n0 = (b % 3) * 128;
        const int lr = lane & 15, lq = lane >> 4;
        f32x4 acc[4][4];
        #pragma unroll
        for (int i = 0; i < 4; ++i)
            #pragma unroll
            for (int j = 0; j < 4; ++j) { acc[i][j][0]=0.f; acc[i][j][1]=0.f; acc[i][j][2]=0.f; acc[i][j][3]=0.f; }
        for (int k0 = 0; k0 < EE; k0 += 32) {
            #pragma unroll
            for (int v = tid; v < 512; v += 256) {
                const int row = v >> 2, cv = (v & 3) << 3;
                const int gk = k0 + cv;
                const int gm = m0 + row, gn = n0 + row;
                bf16x8 va = {}, vb = {};
                if (gm < KF) va = *(const bf16x8*)(Kcat + (long)gm * EE + gk);
                if (gn < EE) vb = *(const bf16x8*)(Qc + (long)gn * EE + gk);
                *(bf16x8*)&As[row][cv] = va;
                *(bf16x8*)&Bs[row][cv] = vb;
            }
            __syncthreads();
            bf16x8 af[4], bfv[4];
            #pragma unroll
            for (int i = 0; i < 4; ++i) af[i] = *(const bf16x8*)&As[wr + i * 16 + lr][lq * 8];
            #pragma unroll
            for (int j = 0; j < 4; ++j) bfv[j] = *(const bf16x8*)&Bs[wc + j * 16 + lr][lq * 8];
            #pragma unroll
            for (int i = 0; i < 4; ++i)
                #pragma unroll
                for (int j = 0; j < 4; ++j)
                    acc[i][j] = __builtin_amdgcn_mfma_f32_16x16x32_bf16(af[i], bfv[j], acc[i][j], 0, 0, 0);
            __syncthreads();
        }
        #pragma unroll
        for (int i = 0; i < 4; ++i)
            #pragma unroll
            for (int j = 0; j < 4; ++j) {
                const int gn = n0 + wc + j * 16 + lr;
                if (gn >= EE) continue;
                #pragma unroll
                for (int r = 0; r < 4; ++r) {
                    const int gm = m0 + wr + i * 16 + lq * 4 + r;
                    if (gm < KF) M2T[(long)gm * EE + gn] = (nbf)acc[i][j][r];
                }
            }
        return;
    }
    if (b < 21) {
        const int c = (b - 18) * 256 + tid;
        if (c < KF) {
            const nbf* kr = Kcat + (long)c * EE;
            float acc = 0.f;
            for (int e = 0; e < EE; ++e) acc += bqc[e] * (float)kr[e];
            bT[c] = acc;
        }
        return;
    }
    // region C: Ut rows for dir d + WWTa column d
    const int d = b - 21;
    float (*Wf)[EE] = (float(*)[EE])smem;       // 30x320 f32 = 38.4 KB
    for (int v = tid; v < OUTD * EE; v += 256) Wf[v / EE][v % EE] = WfinT_f[v];
    __syncthreads();
    if (tid < OUTD) {
        const nbf* vr = VcatN + (long)(640 + d) * EE;
        float acc = 0.f;
        for (int e = 0; e < EE; ++e) acc += Wf[tid][e] * (float)vr[e];
        WWTa[tid * 2 + d] = acc;
    }
    for (int v = tid; v < 2 * EE; v += 256)
        Ut[(long)(d * 32 + 30 + v / EE) * EE + (v % EE)] = (nbf)0.f;
    for (int e = tid; e < EE; e += 256) {
        const nbf* vrow = VcatN + (long)(d * 320 + e) * EE;
        float acc[OUTD];
        #pragma unroll
        for (int j = 0; j < OUTD; ++j) acc[j] = 0.f;
        for (int a = 0; a < EE; ++a) {
            const float v = (float)vrow[a];
            #pragma unroll
            for (int j = 0; j < OUTD; ++j) acc[j] += Wf[j][a] * v;
        }
        for (int j = 0; j < OUTD; ++j)
            Ut[(long)(d * 32 + j) * EE + e] = (nbf)acc[j];
    }
}

// ---------------------------------------------------------------------------
// row0: per-node single-query in-dir attention -> Orow0[node][320] (bf16)
// ---------------------------------------------------------------------------
__global__ __launch_bounds__(256) void row0_kernel(const nbf* __restrict__ P,
        const int* __restrict__ in_idx, nbf* __restrict__ Orow0)
{
    const int tid = threadIdx.x, lane = tid & 63, wave = tid >> 6;
    const int node = blockIdx.x * 4 + wave;
    __shared__ float a_sh[4][16];
    __shared__ int srcs_sh[4][16];
    const int m = lane & 15, q4 = lane >> 4;
    const int src = (m == 0) ? node : in_idx[node * DDEG + m - 1];
    if (q4 == 0) srcs_sh[wave][m] = src;
    const nbf* qrow = P + (long)node * PCOLS;
    const nbf* krow = P + (long)src * PCOLS + 320;
    #pragma unroll
    for (int h = 0; h < NH; ++h) {
        float s = 0.f;
        bf16x8 q1 = *(const bf16x8*)(qrow + h * 64 + q4 * 16);
        bf16x8 q2 = *(const bf16x8*)(qrow + h * 64 + q4 * 16 + 8);
        bf16x8 k1 = *(const bf16x8*)(krow + h * 64 + q4 * 16);
        bf16x8 k2 = *(const bf16x8*)(krow + h * 64 + q4 * 16 + 8);
        #pragma unroll
        for (int j = 0; j < 8; ++j)
            s += (float)q1[j] * (float)k1[j] + (float)q2[j] * (float)k2[j];
        s += __shfl_xor(s, 16);
        s += __shfl_xor(s, 32);
        s *= 0.125f;
        float mxv = s;
        #pragma unroll
        for (int msk = 8; msk >= 1; msk >>= 1) mxv = fmaxf(mxv, __shfl_xor(mxv, msk));
        float e = __expf(s - mxv);
        float es = e;
        #pragma unroll
        for (int msk = 8; msk >= 1; msk >>= 1) es += __shfl_xor(es, msk);
        if (q4 == 0) a_sh[wave][m] = e / es;
        float o = 0.f;
        #pragma unroll
        for (int mm = 0; mm < 16; ++mm)
            o += a_sh[wave][mm] * (float)P[(long)srcs_sh[wave][mm] * PCOLS + 640 + h * 64 + lane];
        Orow0[(long)node * EE + h * 64 + lane] = (nbf)o;
    }
}

// ---------------------------------------------------------------------------
// attn_y: per (node,dir) block (320 thr = 5 waves = heads). Y B-frags
// (Ut + smuggled T row) prefetched at kernel top.
// ---------------------------------------------------------------------------
__global__ __launch_bounds__(320) void attn_y_kernel(const nbf* __restrict__ P,
        const int* __restrict__ in_idx, const int* __restrict__ out_idx,
        const nbf* __restrict__ Tb, const nbf* __restrict__ Ut,
        float* __restrict__ Ygl, int node_base)
{
    const int bx = blockIdx.x;
    const int lnode = bx >> 1, d = bx & 1;
    const int node = node_base + lnode;
    const int tid = threadIdx.x;
    const int lane = tid & 63, wave = tid >> 6;      // wave == head
    __shared__ __align__(16) nbf v_s[16][328];       // V, then O overlay per slab
    __shared__ __align__(16) nbf p_s[NH][16][16];
    __shared__ float Yp[NH][16][32];
    const int* idx = d ? out_idx : in_idx;
    const long coloff = (long)d * 960;
    const int lr = lane & 15, lq = lane >> 4;
    // ---- prefetch Y B-frags (independent of everything) ----
    const nbf* Utd = Ut + (long)d * 32 * EE;
    const nbf* TbRow = Tb + (long)node * TSTB + (long)d * 320;
    bf16x8 yb[2][2];
    #pragma unroll
    for (int c = 0; c < 2; ++c)
        #pragma unroll
        for (int nt = 0; nt < 2; ++nt) {
            const int kk = wave * 64 + c * 32 + lq * 8;
            const int row = nt * 16 + lr;
            yb[c][nt] = *(const bf16x8*)((row == 31) ? (TbRow + kk)
                                                     : (Utd + (long)row * EE + kk));
        }
    // ---- stage V ----
    #pragma unroll
    for (int v = tid; v < 640; v += 320) {
        const int row = v / 40, c8 = (v % 40) * 8;
        const int src = (row == 0) ? node : idx[node * DDEG + row - 1];
        *(bf16x8*)&v_s[row][c8] = *(const bf16x8*)(P + (long)src * PCOLS + coloff + 640 + c8);
    }
    // ---- Q/K direct from global; QK^T overlaps V staging ----
    const int msrc = (lr == 0) ? node : idx[node * DDEG + lr - 1];
    const nbf* prow = P + (long)msrc * PCOLS + coloff;
    f32x4 sc = {0.f, 0.f, 0.f, 0.f};
    #pragma unroll
    for (int c = 0; c < 2; ++c) {
        bf16x8 aq = *(const bf16x8*)(prow + wave * 64 + c * 32 + lq * 8);
        bf16x8 bk = *(const bf16x8*)(prow + 320 + wave * 64 + c * 32 + lq * 8);
        sc = __builtin_amdgcn_mfma_f32_16x16x32_bf16(aq, bk, sc, 0, 0, 0);
    }
    // ---- softmax over m (= lane&15) ----
    float pr[4], mx4[4], sm4[4];
    #pragma unroll
    for (int r = 0; r < 4; ++r) { pr[r] = sc[r] * 0.125f; mx4[r] = pr[r]; }
    #pragma unroll
    for (int msk = 8; msk >= 1; msk >>= 1)
        #pragma unroll
        for (int r = 0; r < 4; ++r) mx4[r] = fmaxf(mx4[r], __shfl_xor(mx4[r], msk));
    #pragma unroll
    for (int r = 0; r < 4; ++r) { pr[r] = __expf(pr[r] - mx4[r]); sm4[r] = pr[r]; }
    #pragma unroll
    for (int msk = 8; msk >= 1; msk >>= 1)
        #pragma unroll
        for (int r = 0; r < 4; ++r) sm4[r] += __shfl_xor(sm4[r], msk);
    #pragma unroll
    for (int r = 0; r < 4; ++r) p_s[wave][lq * 4 + r][lr] = (nbf)(pr[r] / sm4[r]);
    union { bf16x8 v8; nbf e[8]; } pf;
    #pragma unroll
    for (int j = 0; j < 8; ++j) pf.e[j] = (nbf)0.f;
    if (lq < 2) pf.v8 = *(const bf16x8*)&p_s[wave][lr][lq * 8];
    __syncthreads();   // v_s ready
    // ---- AV; O overlaid into this wave's own (consumed) V col-slab ----
    #pragma unroll
    for (int t = 0; t < 4; ++t) {
        const int e0 = wave * 64 + t * 16;
        union { bf16x8 v8; nbf e[8]; } af;
        #pragma unroll
        for (int j = 0; j < 8; ++j) af.e[j] = (nbf)0.f;
        if (lq < 2) {
            #pragma unroll
            for (int j = 0; j < 8; ++j) af.e[j] = v_s[lq * 8 + j][e0 + lr];
        }
        f32x4 ov = {0.f, 0.f, 0.f, 0.f};
        ov = __builtin_amdgcn_mfma_f32_16x16x32_bf16(af.v8, pf.v8, ov, 0, 0, 0);
        union { unsigned long long u; nbf e[4]; } o4;
        #pragma unroll
        for (int r = 0; r < 4; ++r) o4.e[r] = (nbf)ov[r];
        *(unsigned long long*)&v_s[lr][e0 + lq * 4] = o4.u;   // O[l=lr][..]
    }
    // ---- Y partials over this wave's 64-e slab (same-wave LDS ordering) ----
    f32x4 yacc[2];
    yacc[0][0]=0.f; yacc[0][1]=0.f; yacc[0][2]=0.f; yacc[0][3]=0.f;
    yacc[1][0]=0.f; yacc[1][1]=0.f; yacc[1][2]=0.f; yacc[1][3]=0.f;
    const int e0w = wave * 64;
    #pragma unroll
    for (int c = 0; c < 2; ++c) {
        const int kk = e0w + c * 32 + lq * 8;
        bf16x8 afy = *(const bf16x8*)&v_s[lr][kk];
        #pragma unroll
        for (int nt = 0; nt < 2; ++nt)
            yacc[nt] = __builtin_amdgcn_mfma_f32_16x16x32_bf16(afy, yb[c][nt], yacc[nt], 0, 0, 0);
    }
    #pragma unroll
    for (int nt = 0; nt < 2; ++nt)
        #pragma unroll
        for (int r = 0; r < 4; ++r)
            Yp[wave][lq * 4 + r][nt * 16 + lr] = yacc[nt][r];
    __syncthreads();
    // ---- cross-wave reduce + coalesced 2KB store ----
    float* yout = Ygl + (long)(lnode * 2 + d) * 512;
    for (int v = tid; v < 512; v += 320) {
        float sme = 0.f;
        #pragma unroll
        for (int w = 0; w < NH; ++w) sme += Yp[w][v >> 5][v & 31];
        yout[v] = sme;
    }
}

// ---------------------------------------------------------------------------
// combine: 4 nodes/block, one wave per node.
// ---------------------------------------------------------------------------
__global__ __launch_bounds__(256) void combine_kernel(const float* __restrict__ Ygl,
        const nbf* __restrict__ Tb, const float* __restrict__ WWTa,
        const float* __restrict__ bfin, void* __restrict__ out,
        long obase, int cnt, const int* __restrict__ flag)
{
    const int tid = threadIdx.x, lane = tid & 63, wave = tid >> 6;
    const int node = blockIdx.x * 4 + wave;
    const int nodec = (node < cnt) ? node : (cnt - 1);
    __shared__ float Yl[4][1024];
    __shared__ float sf[4][32];
    const float* ysrc = Ygl + (long)nodec * 1024;
    #pragma unroll
    for (int v = lane; v < 1024; v += 64) Yl[wave][v] = ysrc[v];
    if (lane < 32) {
        const int d = lane >> 4, m = lane & 15;
        sf[wave][lane] = (Yl[wave][d * 512 + m * 32 + 31]
                          + (float)Tb[(long)nodec * TSTB + 640 + d]) * 0.05590169943749474f;
    }
    float mx = -1e30f;
    #pragma unroll 4
    for (int m = 0; m < 32; ++m) mx = fmaxf(mx, sf[wave][m]);
    float esum = 0.f, a_in = 0.f, a_out = 0.f;
    #pragma unroll 4
    for (int m = 0; m < 32; ++m) {
        float e = __expf(sf[wave][m] - mx);
        esum += e;
        if (m < 16) a_in += e; else a_out += e;
    }
    const float inv = 1.f / esum;
    a_in *= inv; a_out *= inv;
    const int j = lane;
    if (j < OUTD && node < cnt) {
        float acc = 0.f;
        #pragma unroll 4
        for (int dm = 0; dm < 32; ++dm) {
            const int d = dm >> 4, m = dm & 15;
            float a = __expf(sf[wave][dm] - mx) * inv;
            acc += a * Yl[wave][d * 512 + m * 32 + j];
        }
        float r = acc + a_in * WWTa[j * 2] + a_out * WWTa[j * 2 + 1] + bfin[j];
        r = r > 0.f ? r : expm1f(r);
        if (*flag) ((bf16*)out)[obase + (long)node * OUTD + j] = __float2bfloat16(r);
        else       ((float*)out)[obase + (long)node * OUTD + j] = r;
    }
}

// ---------------------------------------------------------------------------
extern "C" void kernel_launch(void* const* d_in, const int* in_sizes, int n_in,
                              void* d_out, int out_size, void* d_ws, size_t ws_size,
                              hipStream_t stream)
{
    const int* in_idx  = (const int*)d_in[1];
    const int* out_idx = (const int*)d_in[2];

    char* p = (char*)d_ws;
    auto alloc = [&](size_t bytes) { char* r = p; p += (bytes + 255) & ~(size_t)255; return r; };
    const size_t EE2 = (size_t)EE * EE;
    int*   flag       = (int*)alloc(256);
    nbf*   X_bf       = (nbf*)alloc((size_t)NNODE * EE * 2);
    nbf*   qkvw6_bf   = (nbf*)alloc(6 * EE2 * 2);
    nbf*   Wg6_bf     = (nbf*)alloc(6 * EE2 * 2);
    nbf*   qkvw_fin_bf= (nbf*)alloc(3 * EE2 * 2);
    nbf*   owT        = (nbf*)alloc(3 * EE2 * 2);
    float* qkvw_fin_f = (float*)alloc(3 * EE2 * 4);
    float* qkvb_fin_f = (float*)alloc(3 * EE * 4);
    float* bcat       = (float*)alloc(PCOLS * 4);
    float* ob_in_f    = (float*)alloc(EE * 4);
    float* ob_out_f   = (float*)alloc(EE * 4);
    float* ob_fin_f   = (float*)alloc(EE * 4);
    float* W_f        = (float*)alloc((size_t)EE * OUTD * 4);
    float* ow_fin_f   = (float*)alloc(EE2 * 4);
    // composed
    nbf*   AcatT  = (nbf*)alloc((size_t)PCOLS * EE * 2);
    nbf*   Qc_bf  = (nbf*)alloc(EE2 * 2);
    nbf*   Kcat   = (nbf*)alloc((size_t)KF * EE * 2);
    float* bqc_in = (float*)alloc(EE * 4);
    nbf*   M2T    = (nbf*)alloc((size_t)KF * EE * 2);
    float* bT     = (float*)alloc(KF * 4);
    nbf*   VcatN  = (nbf*)alloc((size_t)KF * EE * 2);
    float* WfinT_f= (float*)alloc((size_t)OUTD * EE * 4);
    float* WWTa   = (float*)alloc(64 * 4);
    float* bfin   = (float*)alloc(64 * 4);
    nbf*   Ut     = (nbf*)alloc((size_t)64 * EE * 2);
    nbf*   P      = (nbf*)alloc((size_t)NNODE * PCOLS * 2);
    nbf*   Orow0  = (nbf*)alloc((size_t)NNODE * EE * 2);
    nbf*   Tb     = (nbf*)alloc((size_t)NNODE * TSTB * 2);
    size_t fixed = (size_t)(p - (char*)d_ws);

    const size_t per_node = 1024 * 4;
    size_t avail = (ws_size > fixed + 65536) ? (ws_size - fixed - 65536) : 0;
    long chunk_l = (long)(avail / per_node);
    chunk_l = (chunk_l / 4) * 4;
    int chunk = (chunk_l > NNODE) ? NNODE : (chunk_l < 4 ? 4 : (int)chunk_l);
    float* Ygl = (float*)alloc((size_t)chunk * 1024 * 4);

    dim3 blk(256);
    // ---- prep: detect + all converts + transposes in ONE launch ----
    PrepTab pt;
    pt.xsrc = d_in[0]; pt.xdst = X_bf; pt.xblocks = (NNODE * EE + 255) / 256;
    pt.tsrc0 = d_in[8]; pt.tsrc1 = d_in[15]; pt.tsrc2 = d_in[19]; pt.tdst = owT;
    pt.flag = flag;
    int s = 0;
    auto seg = [&](const void* src, void* dst, int n, int tobf) {
        pt.seg_src[s] = src; pt.seg_dst[s] = dst; pt.seg_n[s] = n;
        pt.seg_tobf[s] = tobf; pt.seg_blocks[s] = (n + 255) / 256; ++s;
    };
    seg(d_in[6],  qkvw6_bf,           (int)(3 * EE2), 1);
    seg(d_in[13], qkvw6_bf + 3 * EE2, (int)(3 * EE2), 1);
    seg(d_in[3],  Wg6_bf + 0 * EE2, (int)EE2, 1);
    seg(d_in[4],  Wg6_bf + 1 * EE2, (int)EE2, 1);
    seg(d_in[5],  Wg6_bf + 2 * EE2, (int)EE2, 1);
    seg(d_in[10], Wg6_bf + 3 * EE2, (int)EE2, 1);
    seg(d_in[11], Wg6_bf + 4 * EE2, (int)EE2, 1);
    seg(d_in[12], Wg6_bf + 5 * EE2, (int)EE2, 1);
    seg(d_in[17], qkvw_fin_bf, (int)(3 * EE2), 1);
    seg(d_in[17], qkvw_fin_f,  (int)(3 * EE2), 0);
    seg(d_in[18], qkvb_fin_f, 3 * EE, 0);
    seg(d_in[7],  bcat,       3 * EE, 0);
    seg(d_in[14], bcat + 960, 3 * EE, 0);
    seg(d_in[9],  ob_in_f,  EE, 0);
    seg(d_in[16], ob_out_f, EE, 0);
    seg(d_in[20], ob_fin_f, EE, 0);
    seg(d_in[21], W_f, EE * OUTD, 0);
    seg(d_in[19], ow_fin_f, (int)EE2, 0);
    int total_blocks = pt.xblocks + 300;
    for (int i = 0; i < NSEG; ++i) total_blocks += pt.seg_blocks[i];
    prep_kernel<<<total_blocks, blk, 0, stream>>>(pt);

    // ---- compose GEMMs (pure, 11 z-slices) ----
    JobTab jt;
    for (int g = 0; g < 6; ++g) {
        jt.A[g] = qkvw6_bf + (size_t)g * EE2;
        jt.B[g] = Wg6_bf + (size_t)g * EE2;
        jt.C[g] = AcatT + (size_t)g * EE2;
    }
    jt.A[6] = owT;        jt.B[6] = qkvw_fin_bf;                      jt.C[6] = Qc_bf;
    jt.A[7] = owT;        jt.B[7] = qkvw_fin_bf + (size_t)320 * EE;   jt.C[7] = Kcat;
    jt.A[8] = owT + EE2;  jt.B[8] = qkvw_fin_bf + (size_t)320 * EE;   jt.C[8] = Kcat + (size_t)320 * EE;
    jt.A[9] = owT;        jt.B[9] = qkvw_fin_bf + (size_t)640 * EE;   jt.C[9] = VcatN;
    jt.A[10]= owT + EE2;  jt.B[10]= qkvw_fin_bf + (size_t)640 * EE;   jt.C[10]= VcatN + (size_t)320 * EE;
    gemm_mfma_jobs<<<dim3(3, 3, NJOB), blk, 0, stream>>>(jt);

    // ---- bias/bfin + WfinT (efficient small kernels) ----
    compose_bias_bfin_kernel<<<6, dim3(320), 0, stream>>>(
        ob_in_f, ob_out_f, qkvw_fin_f, qkvb_fin_f, ob_fin_f, W_f,
        bqc_in, Kcat, VcatN, bfin);
    gemm_k<true, false, float><<<dim3(5, 1), blk, 0, stream>>>(
        W_f, OUTD, ow_fin_f, EE, nullptr, WfinT_f, EE, OUTD, EE, EE);

    // ---- P = X @ Acat + bcat ----
    gemm_mfma<bf16><<<dim3(PCOLS / 128, (NNODE + 127) / 128), blk, 0, stream>>>(
        X_bf, EE, AcatT, EE, bcat, (bf16*)P, PCOLS, NNODE, PCOLS, EE);

    // ---- M2T + bT + Ut + WWTa in ONE launch ----
    finalize_kernel<<<23, blk, 0, stream>>>(Kcat, Qc_bf, bqc_in, VcatN, WfinT_f,
                                            M2T, bT, Ut, WWTa);

    // ---- row0 in-attention -> Orow0 ----
    row0_kernel<<<NNODE / 4, blk, 0, stream>>>(P, in_idx, Orow0);

    // ---- T = Orow0 @ M2T + bT -> bf16, padded stride TSTB ----
    gemm_mfma<bf16><<<dim3((KF + 127) / 128, (NNODE + 127) / 128), blk, 0, stream>>>(
        Orow0, EE, M2T, EE, bT, (bf16*)Tb, TSTB, NNODE, KF, EE);

    // ---- per-node pipeline (chunked over Y buffer) ----
    for (int base = 0; base < NNODE; base += chunk) {
        int cnt = (NNODE - base < chunk) ? (NNODE - base) : chunk;
        attn_y_kernel<<<2 * cnt, dim3(320), 0, stream>>>(
            P, in_idx, out_idx, Tb, Ut, Ygl, base);
        combine_kernel<<<(cnt + 3) / 4, blk, 0, stream>>>(
            Ygl, Tb + (size_t)base * TSTB, WWTa, bfin, d_out, (long)base * OUTD, cnt, flag);
    }
}